// Round 6
// baseline (179.912 us; speedup 1.0000x reference)
//
#include <hip/hip_runtime.h>
#include <stdint.h>

#define SS 256
#define FAR_F 100.0f
#define REG 32             // region size in px
#define NREG 64            // regions per batch (8x8)
#define CAPP 576           // partial-face LDS capacity
#define CAPF 160           // full-face LDS capacity
#define SORTN 1024         // sort array size (pow2 >= CAPP)
#define OVN  1544          // overflow list capacity (>= F)

struct __align__(16) PackedCoef {
    float4 q0;  // A0,B0,C0,A1   (edge coefs premultiplied by inv_area)
    float4 q1;  // B1,C1,Zx,Zy   (zinv = Z0 + Zx*px + Zy*py)
    float4 q2;  // Z0, e_face, bits(bbox), bits(faceid)
};

// ---------------- prep: per (b,f) packed coefficients + bbox ----------------
__global__ void nmr_prep(const float* __restrict__ verts,
                         const int* __restrict__ faces,
                         PackedCoef* __restrict__ pc,
                         uint32_t* __restrict__ bbx,
                         int B, int N, int F)
{
#pragma clang fp contract(off)
    int idx = blockIdx.x * blockDim.x + threadIdx.x;
    if (idx >= B * F) return;
    int b = idx / F;
    int f = idx - b * F;

    int i0 = faces[3 * f + 0], i1 = faces[3 * f + 1], i2 = faces[3 * f + 2];
    const float* vb = verts + (size_t)(3 * N) * b;
    const float EZ = -1.7320508075688772f;  // f32(EYE_Z)

    float x0 = vb[3 * i0 + 0], y0 = -vb[3 * i0 + 1], z0 = vb[3 * i0 + 2] - EZ;
    float x1 = vb[3 * i1 + 0], y1 = -vb[3 * i1 + 1], z1 = vb[3 * i1 + 2] - EZ;
    float x2 = vb[3 * i2 + 0], y2 = -vb[3 * i2 + 1], z2 = vb[3 * i2 + 2] - EZ;

    float area = (x1 - x0) * (y2 - y0) - (x2 - x0) * (y1 - y0);
    bool ok = fabsf(area) > 1e-7f;
    float ia = ok ? (1.0f / area) : 0.0f;

    float A0 = (x1 * y2 - x2 * y1) * ia, B0 = (y1 - y2) * ia, C0 = (x2 - x1) * ia;
    float A1 = (x2 * y0 - x0 * y2) * ia, B1 = (y2 - y0) * ia, C1 = (x0 - x2) * ia;
    float rz0 = 1.0f / z0, rz1 = 1.0f / z1, rz2 = 1.0f / z2;
    float d0 = rz0 - rz2, d1 = rz1 - rz2;
    float Z0 = rz2 + A0 * d0 + A1 * d1;
    float Zx = B0 * d0 + B1 * d1;
    float Zy = C0 * d0 + C1 * d1;
    // rigorous per-face ambiguity half-width (|px|,|py|<1)
    float S = fabsf(A0) + fabsf(B0) + fabsf(C0) + fabsf(A1) + fabsf(B1) + fabsf(C1) + 1.0f;
    float ef = 3e-6f * S;

    uint32_t bb = 255u | (0u << 8) | (255u << 16) | (0u << 24);
    if (ok) {
        float xmn = fminf(x0, fminf(x1, x2)), xmx = fmaxf(x0, fmaxf(x1, x2));
        float ymn = fminf(y0, fminf(y1, y2)), ymx = fmaxf(y0, fmaxf(y1, y2));
        int jlo = (int)floorf(128.0f * (xmn + 1.0f) - 0.5f) - 1;
        int jhi = (int)ceilf (128.0f * (xmx + 1.0f) - 0.5f) + 1;
        int ilo = (int)floorf((255.0f - 256.0f * ymx) * 0.5f) - 1;
        int ihi = (int)ceilf ((255.0f - 256.0f * ymn) * 0.5f) + 1;
        jlo = max(0, min(255, jlo)); jhi = max(0, min(255, jhi));
        ilo = max(0, min(255, ilo)); ihi = max(0, min(255, ihi));
        if (jhi >= jlo && ihi >= ilo)
            bb = (uint32_t)jlo | ((uint32_t)jhi << 8) | ((uint32_t)ilo << 16) | ((uint32_t)ihi << 24);
    }

    PackedCoef c;
    c.q0 = make_float4(A0, B0, C0, A1);
    c.q1 = make_float4(B1, C1, Zx, Zy);
    c.q2 = make_float4(Z0, ef, __uint_as_float(bb), __uint_as_float((uint32_t)f));
    pc[idx] = c;
    bbx[idx] = bb;
}

// full face body (inside test + amb fallback); caller has done bbox/key skips
__device__ __forceinline__ void face_body(
    float4 q0, float4 q1, float4 q2,
    float px, float py0, float py1, float py2, float py3,
    const float* __restrict__ verts, const int* __restrict__ faces, int N, int b,
    float& best0, float& best1, float& best2, float& best3)
{
#pragma clang fp contract(off)
    const float ef = q2.y;
    float w0b = __builtin_fmaf(q0.y, px, q0.x);
    float w1b = __builtin_fmaf(q1.x, px, q0.w);
    float zbv = __builtin_fmaf(q1.z, px, q2.x);

    float w0_0 = __builtin_fmaf(q0.z, py0, w0b), w1_0 = __builtin_fmaf(q1.y, py0, w1b);
    float w0_1 = __builtin_fmaf(q0.z, py1, w0b), w1_1 = __builtin_fmaf(q1.y, py1, w1b);
    float w0_2 = __builtin_fmaf(q0.z, py2, w0b), w1_2 = __builtin_fmaf(q1.y, py2, w1b);
    float w0_3 = __builtin_fmaf(q0.z, py3, w0b), w1_3 = __builtin_fmaf(q1.y, py3, w1b);
    float m0 = fminf(w0_0, fminf(w1_0, (1.0f - w0_0) - w1_0));
    float m1 = fminf(w0_1, fminf(w1_1, (1.0f - w0_1) - w1_1));
    float m2 = fminf(w0_2, fminf(w1_2, (1.0f - w0_2) - w1_2));
    float m3 = fminf(w0_3, fminf(w1_3, (1.0f - w0_3) - w1_3));
    float zi0 = __builtin_fmaf(q1.w, py0, zbv);
    float zi1 = __builtin_fmaf(q1.w, py1, zbv);
    float zi2 = __builtin_fmaf(q1.w, py2, zbv);
    float zi3 = __builtin_fmaf(q1.w, py3, zbv);
    bool ins0 = m0 >= 0.0f, ins1 = m1 >= 0.0f, ins2 = m2 >= 0.0f, ins3 = m3 >= 0.0f;
    bool amb = (fabsf(m0) <= ef) | (fabsf(m1) <= ef) | (fabsf(m2) <= ef) | (fabsf(m3) <= ef);

    if (__any(amb)) {
        // exact numpy-order recompute (rare); staged faces are non-degenerate
        int fid = __builtin_amdgcn_readfirstlane((int)__float_as_uint(q2.w));
        int i0f = faces[3 * fid + 0], i1f = faces[3 * fid + 1], i2f = faces[3 * fid + 2];
        const float* vb = verts + (size_t)(3 * N) * b;
        float x0 = vb[3 * i0f + 0], y0 = -vb[3 * i0f + 1];
        float x1 = vb[3 * i1f + 0], y1 = -vb[3 * i1f + 1];
        float x2 = vb[3 * i2f + 0], y2 = -vb[3 * i2f + 1];
        float area = (x1 - x0) * (y2 - y0) - (x2 - x0) * (y1 - y0);
        float ia = 1.0f / area;
        float a0 = x1 * y2 - x2 * y1, b0e = y1 - y2, c0e = x2 - x1;
        float a1 = x2 * y0 - x0 * y2, b1e = y2 - y0, c1e = x0 - x2;
        float e0b = a0 + b0e * px;
        float e1b = a1 + b1e * px;
        { float u0 = (e0b + c0e * py0) * ia, u1 = (e1b + c1e * py0) * ia;
          ins0 = fminf(u0, fminf(u1, (1.0f - u0) - u1)) >= 0.0f; }
        { float u0 = (e0b + c0e * py1) * ia, u1 = (e1b + c1e * py1) * ia;
          ins1 = fminf(u0, fminf(u1, (1.0f - u0) - u1)) >= 0.0f; }
        { float u0 = (e0b + c0e * py2) * ia, u1 = (e1b + c1e * py2) * ia;
          ins2 = fminf(u0, fminf(u1, (1.0f - u0) - u1)) >= 0.0f; }
        { float u0 = (e0b + c0e * py3) * ia, u1 = (e1b + c1e * py3) * ia;
          ins3 = fminf(u0, fminf(u1, (1.0f - u0) - u1)) >= 0.0f; }
    }
    best0 = ins0 ? fmaxf(best0, zi0) : best0;
    best1 = ins1 ? fmaxf(best1, zi1) : best1;
    best2 = ins2 ? fmaxf(best2, zi2) : best2;
    best3 = ins3 ? fmaxf(best3, zi3) : best3;
}

// ---------------- raster: one block per (batch, 32x32 region) ----------------
__global__ __launch_bounds__(256, 4) void nmr_raster(
    const PackedCoef* __restrict__ pc,
    const uint32_t* __restrict__ bbx,
    const float* __restrict__ verts,
    const int* __restrict__ faces,
    float* __restrict__ out,
    int B, int N, int F)
{
#pragma clang fp contract(off)
    __shared__ float4   pool[3 * CAPP];   // partial records
    __shared__ float4   fullr[CAPF];      // full-inside records: Z0,Zx,Zy,key
    __shared__ uint32_t sukey[SORTN];     // sort keys: zmax-bits(hi20) | pool idx(lo12)
    __shared__ uint32_t sbb[CAPP];        // partial face bboxes
    __shared__ uint16_t ovl[OVN];         // overflow face ids
    __shared__ int cnt_p, cnt_f, cnt_o;

    const int tid = threadIdx.x;
    const int bid = blockIdx.x;
    const int reg = bid % NREG; const int b = bid / NREG;
    const int rj0 = (reg & 7) * REG;
    const int ri0 = (reg >> 3) * REG;

    if (tid == 0) { cnt_p = 0; cnt_f = 0; cnt_o = 0; }
    for (int i = tid; i < SORTN; i += 256) sukey[i] = 0;
    __syncthreads();

    // ---- phase 1: cull -> classify -> stage ----
    const uint32_t* bb = bbx + (size_t)b * F;
    const PackedCoef* pb = pc + (size_t)b * F;

    const float cxa = (float)(2 * rj0 + 1 - SS) * (1.0f / SS);
    const float cxb = (float)(2 * (rj0 + REG - 1) + 1 - SS) * (1.0f / SS);
    const float cya = (float)(SS - 1 - 2 * ri0) * (1.0f / SS);
    const float cyb = (float)(SS - 1 - 2 * (ri0 + REG - 1)) * (1.0f / SS);

    for (int f = tid; f < F; f += 256) {
        uint32_t v = bb[f];
        int jlo = v & 255, jhi = (v >> 8) & 255, ilo = (v >> 16) & 255, ihi = (int)(v >> 24);
        if (jlo > rj0 + REG - 1 || jhi < rj0 || ilo > ri0 + REG - 1 || ihi < ri0) continue;
        PackedCoef P = pb[f];
        float b0a = __builtin_fmaf(P.q0.y, cxa, P.q0.x), b0b = __builtin_fmaf(P.q0.y, cxb, P.q0.x);
        float w0aa = __builtin_fmaf(P.q0.z, cya, b0a), w0ab = __builtin_fmaf(P.q0.z, cyb, b0a);
        float w0ba = __builtin_fmaf(P.q0.z, cya, b0b), w0bb = __builtin_fmaf(P.q0.z, cyb, b0b);
        float b1a = __builtin_fmaf(P.q1.x, cxa, P.q0.w), b1b = __builtin_fmaf(P.q1.x, cxb, P.q0.w);
        float w1aa = __builtin_fmaf(P.q1.y, cya, b1a), w1ab = __builtin_fmaf(P.q1.y, cyb, b1a);
        float w1ba = __builtin_fmaf(P.q1.y, cya, b1b), w1bb = __builtin_fmaf(P.q1.y, cyb, b1b);
        float w2aa = (1.0f - w0aa) - w1aa, w2ab = (1.0f - w0ab) - w1ab;
        float w2ba = (1.0f - w0ba) - w1ba, w2bb = (1.0f - w0bb) - w1bb;

        float m0n = fminf(fminf(w0aa, w0ab), fminf(w0ba, w0bb));
        float m0x = fmaxf(fmaxf(w0aa, w0ab), fmaxf(w0ba, w0bb));
        float m1n = fminf(fminf(w1aa, w1ab), fminf(w1ba, w1bb));
        float m1x = fmaxf(fmaxf(w1aa, w1ab), fmaxf(w1ba, w1bb));
        float m2n = fminf(fminf(w2aa, w2ab), fminf(w2ba, w2bb));
        float m2x = fmaxf(fmaxf(w2aa, w2ab), fmaxf(w2ba, w2bb));

        float Rm = 2.0f * P.q2.y;
        if (m0x < -Rm || m1x < -Rm || m2x < -Rm) continue;   // fully outside an edge

        // zinv upper bound over region + conservative margin (clamped >= 0)
        float za = __builtin_fmaf(P.q1.z, cxa, P.q2.x), zbq = __builtin_fmaf(P.q1.z, cxb, P.q2.x);
        float z_aa = __builtin_fmaf(P.q1.w, cya, za),  z_ab = __builtin_fmaf(P.q1.w, cyb, za);
        float z_ba = __builtin_fmaf(P.q1.w, cya, zbq), z_bb = __builtin_fmaf(P.q1.w, cyb, zbq);
        float cmax = fmaxf(fmaxf(z_aa, z_ab), fmaxf(z_ba, z_bb));
        float key = fmaxf(cmax + __builtin_fmaf(fabsf(cmax), 1e-6f, 1e-5f), 0.0f);

        bool full = (m0n > Rm && m1n > Rm && m2n > Rm);
        if (full) {
            int q = atomicAdd(&cnt_f, 1);
            if (q < CAPF) { fullr[q] = make_float4(P.q2.x, P.q1.z, P.q1.w, key); continue; }
        }
        int p = atomicAdd(&cnt_p, 1);
        if (p < CAPP) {
            pool[3 * p + 0] = P.q0; pool[3 * p + 1] = P.q1; pool[3 * p + 2] = P.q2;
            sbb[p] = v;
            uint32_t kb = __float_as_uint(key);
            sukey[p] = ((kb + 0xFFFu) & 0xFFFFF000u) | (uint32_t)p;  // round key UP: conservative
        } else {
            int o = atomicAdd(&cnt_o, 1);
            if (o < OVN) ovl[o] = (uint16_t)f;
        }
    }
    __syncthreads();

    const int np = min(cnt_p, CAPP), nf = min(cnt_f, CAPF), no = min(cnt_o, OVN);

    // ---- sort partial keys descending (bitonic on u32) ----
    if (np > 1) {
        int n2 = 4; while (n2 < np) n2 <<= 1;
        for (int sz = 2; sz <= n2; sz <<= 1) {
            for (int st = sz >> 1; st > 0; st >>= 1) {
                __syncthreads();
                for (int i = tid; i < n2; i += 256) {
                    int pr = i ^ st;
                    if (pr > i) {
                        uint32_t a = sukey[i], c = sukey[pr];
                        bool desc = ((i & sz) == 0);
                        if (desc ? (a < c) : (a > c)) { sukey[i] = c; sukey[pr] = a; }
                    }
                }
            }
        }
    }
    __syncthreads();

    // ---- phase 2 ----
    const int lane = tid & 63, w = tid >> 6;
    const int wj0 = rj0 + ((w & 1) << 4);
    const int wi0 = ri0 + ((w >> 1) << 4);
    const int j = wj0 + (lane & 15);
    const int i0r = wi0 + (lane >> 4);                 // rows i0r + 4r
    const float px = (float)(2 * j + 1 - SS) * (1.0f / SS);
    const float py0 = (float)(SS - 1 - 2 * (i0r + 0))  * (1.0f / SS);
    const float py1 = (float)(SS - 1 - 2 * (i0r + 4))  * (1.0f / SS);
    const float py2 = (float)(SS - 1 - 2 * (i0r + 8))  * (1.0f / SS);
    const float py3 = (float)(SS - 1 - 2 * (i0r + 12)) * (1.0f / SS);

    float best0 = 0.0f, best1 = 0.0f, best2 = 0.0f, best3 = 0.0f;

    // full-inside faces first: raises best cheaply
    for (int k = 0; k < nf; ++k) {
        float4 z = fullr[k];
        float lanemin = fminf(fminf(best0, best1), fminf(best2, best3));
        if (__all(z.w <= lanemin)) continue;
        float zb = __builtin_fmaf(z.y, px, z.x);
        best0 = fmaxf(best0, __builtin_fmaf(z.z, py0, zb));
        best1 = fmaxf(best1, __builtin_fmaf(z.z, py1, zb));
        best2 = fmaxf(best2, __builtin_fmaf(z.z, py2, zb));
        best3 = fmaxf(best3, __builtin_fmaf(z.z, py3, zb));
    }

    // sorted partial faces: front-to-back with wave-level break
    {
        float lanemin = fminf(fminf(best0, best1), fminf(best2, best3));
        uint32_t lmU = __float_as_uint(lanemin);
        for (int g = 0; g < np; g += 4) {
            uint4 kk = *reinterpret_cast<const uint4*>(&sukey[g]);
            if (__all((int)(kk.x <= lmU))) break;     // sorted: all remaining <= too
            uint32_t ee0 = kk.x, ee1 = kk.y, ee2 = kk.z, ee3 = kk.w;
            #pragma unroll
            for (int u = 0; u < 4; ++u) {
                uint32_t e = (u == 0) ? ee0 : (u == 1) ? ee1 : (u == 2) ? ee2 : ee3;
                if ((e >> 12) == 0) continue;          // pad
                if (__all((int)(e <= lmU))) continue;  // occluded everywhere in wave
                int idx = (int)(e & 0xFFFu);
                uint32_t bv = sbb[idx];
                int jlo = bv & 255, jhi = (bv >> 8) & 255, ilo = (bv >> 16) & 255, ihi = (int)(bv >> 24);
                if (jlo > wj0 + 15 || jhi < wj0 || ilo > wi0 + 15 || ihi < wi0) continue;
                face_body(pool[3 * idx + 0], pool[3 * idx + 1], pool[3 * idx + 2],
                          px, py0, py1, py2, py3, verts, faces, N, b,
                          best0, best1, best2, best3);
            }
            lanemin = fminf(fminf(best0, best1), fminf(best2, best3));
            lmU = __float_as_uint(lanemin);
        }
    }

    // overflow faces (rare): direct from global
    for (int k = 0; k < no; ++k) {
        int fid = __builtin_amdgcn_readfirstlane((int)ovl[k]);
        float4 q2 = pb[fid].q2;
        uint32_t bv = __float_as_uint(q2.z);
        int jlo = bv & 255, jhi = (bv >> 8) & 255, ilo = (bv >> 16) & 255, ihi = (int)(bv >> 24);
        if (jlo > wj0 + 15 || jhi < wj0 || ilo > wi0 + 15 || ihi < wi0) continue;
        face_body(pb[fid].q0, pb[fid].q1, q2,
                  px, py0, py1, py2, py3, verts, faces, N, b,
                  best0, best1, best2, best3);
    }

    // ---- epilogue: direct stores (regions partition pixels; no atomics) ----
    const size_t zoff = (size_t)B * (SS * SS);
    const size_t base = (size_t)b * (SS * SS) + (size_t)i0r * SS + j;
    out[base + 0 * 4 * SS] = (best0 > 0.0f) ? 1.0f : 0.0f;
    out[base + 1 * 4 * SS] = (best1 > 0.0f) ? 1.0f : 0.0f;
    out[base + 2 * 4 * SS] = (best2 > 0.0f) ? 1.0f : 0.0f;
    out[base + 3 * 4 * SS] = (best3 > 0.0f) ? 1.0f : 0.0f;
    out[zoff + base + 0 * 4 * SS] = (best0 > 0.0f) ? (1.0f / best0) : FAR_F;
    out[zoff + base + 1 * 4 * SS] = (best1 > 0.0f) ? (1.0f / best1) : FAR_F;
    out[zoff + base + 2 * 4 * SS] = (best2 > 0.0f) ? (1.0f / best2) : FAR_F;
    out[zoff + base + 3 * 4 * SS] = (best3 > 0.0f) ? (1.0f / best3) : FAR_F;
}

// ---------------- host ----------------
extern "C" void kernel_launch(void* const* d_in, const int* in_sizes, int n_in,
                              void* d_out, int out_size, void* d_ws, size_t ws_size,
                              hipStream_t stream)
{
    const float* verts = (const float*)d_in[0];
    const int*   faces = (const int*)d_in[1];
    float* out = (float*)d_out;

    const int B = out_size / (2 * SS * SS);          // 16
    const int F = in_sizes[1] / 3;                   // 1538
    const int N = in_sizes[0] / (3 * B);             // 778

    PackedCoef* pc = (PackedCoef*)d_ws;
    uint32_t*  bbx = (uint32_t*)((char*)d_ws + (size_t)B * F * sizeof(PackedCoef));

    const int total = B * F;
    nmr_prep<<<(total + 255) / 256, 256, 0, stream>>>(verts, faces, pc, bbx, B, N, F);

    nmr_raster<<<B * NREG, 256, 0, stream>>>(pc, bbx, verts, faces, out, B, N, F);
}

// Round 7
// 98.551 us; speedup vs baseline: 1.8256x; 1.8256x over previous
//
#include <hip/hip_runtime.h>
#include <stdint.h>

#define SS 256
#define FAR_F 100.0f
#define REG 32             // region size in px
#define NREG 64            // regions per batch (8x8)
#define NCH 3              // face chunks
#define CAPP 504           // partial-face LDS capacity (CH=513 worst case -> overflow list)
#define CAPF 120           // full-inside LDS capacity
#define OVN  64            // overflow capacity (>= CH - CAPP = 9)

struct __align__(16) PackedCoef {
    float4 q0;  // A0,B0,C0,A1   (edge coefs premultiplied by inv_area)
    float4 q1;  // B1,C1,Zx,Zy   (zinv = Z0 + Zx*px + Zy*py)
    float4 q2;  // Z0, e_face, bits(bbox), bits(faceid)
};

// ---------------- prep: per (b,f) packed coefficients + bbox ----------------
__global__ void nmr_prep(const float* __restrict__ verts,
                         const int* __restrict__ faces,
                         PackedCoef* __restrict__ pc,
                         uint32_t* __restrict__ bbx,
                         int B, int N, int F)
{
#pragma clang fp contract(off)
    int idx = blockIdx.x * blockDim.x + threadIdx.x;
    if (idx >= B * F) return;
    int b = idx / F;
    int f = idx - b * F;

    int i0 = faces[3 * f + 0], i1 = faces[3 * f + 1], i2 = faces[3 * f + 2];
    const float* vb = verts + (size_t)(3 * N) * b;
    const float EZ = -1.7320508075688772f;  // f32(EYE_Z)

    float x0 = vb[3 * i0 + 0], y0 = -vb[3 * i0 + 1], z0 = vb[3 * i0 + 2] - EZ;
    float x1 = vb[3 * i1 + 0], y1 = -vb[3 * i1 + 1], z1 = vb[3 * i1 + 2] - EZ;
    float x2 = vb[3 * i2 + 0], y2 = -vb[3 * i2 + 1], z2 = vb[3 * i2 + 2] - EZ;

    float area = (x1 - x0) * (y2 - y0) - (x2 - x0) * (y1 - y0);
    bool ok = fabsf(area) > 1e-7f;
    float ia = ok ? (1.0f / area) : 0.0f;

    float A0 = (x1 * y2 - x2 * y1) * ia, B0 = (y1 - y2) * ia, C0 = (x2 - x1) * ia;
    float A1 = (x2 * y0 - x0 * y2) * ia, B1 = (y2 - y0) * ia, C1 = (x0 - x2) * ia;
    float rz0 = 1.0f / z0, rz1 = 1.0f / z1, rz2 = 1.0f / z2;
    float d0 = rz0 - rz2, d1 = rz1 - rz2;
    float Z0 = rz2 + A0 * d0 + A1 * d1;
    float Zx = B0 * d0 + B1 * d1;
    float Zy = C0 * d0 + C1 * d1;
    // rigorous per-face ambiguity half-width (|px|,|py|<1)
    float S = fabsf(A0) + fabsf(B0) + fabsf(C0) + fabsf(A1) + fabsf(B1) + fabsf(C1) + 1.0f;
    float ef = 3e-6f * S;

    uint32_t bb = 255u | (0u << 8) | (255u << 16) | (0u << 24);
    if (ok) {
        float xmn = fminf(x0, fminf(x1, x2)), xmx = fmaxf(x0, fmaxf(x1, x2));
        float ymn = fminf(y0, fminf(y1, y2)), ymx = fmaxf(y0, fmaxf(y1, y2));
        int jlo = (int)floorf(128.0f * (xmn + 1.0f) - 0.5f) - 1;
        int jhi = (int)ceilf (128.0f * (xmx + 1.0f) - 0.5f) + 1;
        int ilo = (int)floorf((255.0f - 256.0f * ymx) * 0.5f) - 1;
        int ihi = (int)ceilf ((255.0f - 256.0f * ymn) * 0.5f) + 1;
        jlo = max(0, min(255, jlo)); jhi = max(0, min(255, jhi));
        ilo = max(0, min(255, ilo)); ihi = max(0, min(255, ihi));
        if (jhi >= jlo && ihi >= ilo)
            bb = (uint32_t)jlo | ((uint32_t)jhi << 8) | ((uint32_t)ilo << 16) | ((uint32_t)ihi << 24);
    }

    PackedCoef c;
    c.q0 = make_float4(A0, B0, C0, A1);
    c.q1 = make_float4(B1, C1, Zx, Zy);
    c.q2 = make_float4(Z0, ef, __uint_as_float(bb), __uint_as_float((uint32_t)f));
    pc[idx] = c;
    bbx[idx] = bb;
}

// full face body (inside test + amb fallback); caller has done bbox/key skips
__device__ __forceinline__ void face_body(
    float4 q0, float4 q1, float4 q2,
    float px, float py0, float py1, float py2, float py3,
    const float* __restrict__ verts, const int* __restrict__ faces, int N, int b,
    float& best0, float& best1, float& best2, float& best3)
{
#pragma clang fp contract(off)
    const float ef = q2.y;
    float w0b = __builtin_fmaf(q0.y, px, q0.x);
    float w1b = __builtin_fmaf(q1.x, px, q0.w);
    float zbv = __builtin_fmaf(q1.z, px, q2.x);

    float w0_0 = __builtin_fmaf(q0.z, py0, w0b), w1_0 = __builtin_fmaf(q1.y, py0, w1b);
    float w0_1 = __builtin_fmaf(q0.z, py1, w0b), w1_1 = __builtin_fmaf(q1.y, py1, w1b);
    float w0_2 = __builtin_fmaf(q0.z, py2, w0b), w1_2 = __builtin_fmaf(q1.y, py2, w1b);
    float w0_3 = __builtin_fmaf(q0.z, py3, w0b), w1_3 = __builtin_fmaf(q1.y, py3, w1b);
    float m0 = fminf(w0_0, fminf(w1_0, (1.0f - w0_0) - w1_0));
    float m1 = fminf(w0_1, fminf(w1_1, (1.0f - w0_1) - w1_1));
    float m2 = fminf(w0_2, fminf(w1_2, (1.0f - w0_2) - w1_2));
    float m3 = fminf(w0_3, fminf(w1_3, (1.0f - w0_3) - w1_3));
    float zi0 = __builtin_fmaf(q1.w, py0, zbv);
    float zi1 = __builtin_fmaf(q1.w, py1, zbv);
    float zi2 = __builtin_fmaf(q1.w, py2, zbv);
    float zi3 = __builtin_fmaf(q1.w, py3, zbv);
    bool ins0 = m0 >= 0.0f, ins1 = m1 >= 0.0f, ins2 = m2 >= 0.0f, ins3 = m3 >= 0.0f;
    bool amb = (fabsf(m0) <= ef) | (fabsf(m1) <= ef) | (fabsf(m2) <= ef) | (fabsf(m3) <= ef);

    if (__any(amb)) {
        // exact numpy-order recompute (rare); staged faces are non-degenerate
        int fid = __builtin_amdgcn_readfirstlane((int)__float_as_uint(q2.w));
        int i0f = faces[3 * fid + 0], i1f = faces[3 * fid + 1], i2f = faces[3 * fid + 2];
        const float* vb = verts + (size_t)(3 * N) * b;
        float x0 = vb[3 * i0f + 0], y0 = -vb[3 * i0f + 1];
        float x1 = vb[3 * i1f + 0], y1 = -vb[3 * i1f + 1];
        float x2 = vb[3 * i2f + 0], y2 = -vb[3 * i2f + 1];
        float area = (x1 - x0) * (y2 - y0) - (x2 - x0) * (y1 - y0);
        float ia = 1.0f / area;
        float a0 = x1 * y2 - x2 * y1, b0e = y1 - y2, c0e = x2 - x1;
        float a1 = x2 * y0 - x0 * y2, b1e = y2 - y0, c1e = x0 - x2;
        float e0b = a0 + b0e * px;
        float e1b = a1 + b1e * px;
        { float u0 = (e0b + c0e * py0) * ia, u1 = (e1b + c1e * py0) * ia;
          ins0 = fminf(u0, fminf(u1, (1.0f - u0) - u1)) >= 0.0f; }
        { float u0 = (e0b + c0e * py1) * ia, u1 = (e1b + c1e * py1) * ia;
          ins1 = fminf(u0, fminf(u1, (1.0f - u0) - u1)) >= 0.0f; }
        { float u0 = (e0b + c0e * py2) * ia, u1 = (e1b + c1e * py2) * ia;
          ins2 = fminf(u0, fminf(u1, (1.0f - u0) - u1)) >= 0.0f; }
        { float u0 = (e0b + c0e * py3) * ia, u1 = (e1b + c1e * py3) * ia;
          ins3 = fminf(u0, fminf(u1, (1.0f - u0) - u1)) >= 0.0f; }
    }
    best0 = ins0 ? fmaxf(best0, zi0) : best0;
    best1 = ins1 ? fmaxf(best1, zi1) : best1;
    best2 = ins2 ? fmaxf(best2, zi2) : best2;
    best3 = ins3 ? fmaxf(best3, zi3) : best3;
}

__device__ __forceinline__ float wave_min_f(float x) {
    #pragma unroll
    for (int m = 1; m < 64; m <<= 1) x = fminf(x, __shfl_xor(x, m));
    return x;
}

// ---------------- raster: block = (batch, 32x32 region, face-chunk) ----------------
__global__ __launch_bounds__(256, 5) void nmr_raster(
    const PackedCoef* __restrict__ pc,
    const uint32_t* __restrict__ bbx,
    const float* __restrict__ verts,
    const int* __restrict__ faces,
    uint32_t* __restrict__ zu,
    int B, int N, int F, int CH)
{
#pragma clang fp contract(off)
    __shared__ float4   pool[3 * CAPP];          // partial records
    __shared__ __align__(16) float skey[CAPP + 16];   // partial z-upper-bound keys (padded)
    __shared__ uint32_t sbb[CAPP];               // partial face bboxes
    __shared__ float4   fullr[CAPF];             // full-inside: Z0,Zx,Zy,key
    __shared__ __align__(16) float fkey[CAPF + 16];   // full keys (padded)
    __shared__ uint16_t ovl[OVN];                // overflow face ids
    __shared__ int cnt_p, cnt_f, cnt_o;

    const int tid = threadIdx.x;
    const int bid = blockIdx.x;
    const int ch = bid % NCH; int t = bid / NCH;
    const int reg = t % NREG; const int b = t / NREG;
    const int rj0 = (reg & 7) * REG;
    const int ri0 = (reg >> 3) * REG;

    if (tid == 0) { cnt_p = 0; cnt_f = 0; cnt_o = 0; }
    __syncthreads();

    // ---- phase 1: cull -> classify -> stage + z key ----
    const int f0 = ch * CH, f1 = min(F, f0 + CH);
    const uint32_t* bb = bbx + (size_t)b * F;
    const PackedCoef* pb = pc + (size_t)b * F;

    const float cxa = (float)(2 * rj0 + 1 - SS) * (1.0f / SS);
    const float cxb = (float)(2 * (rj0 + REG - 1) + 1 - SS) * (1.0f / SS);
    const float cya = (float)(SS - 1 - 2 * ri0) * (1.0f / SS);
    const float cyb = (float)(SS - 1 - 2 * (ri0 + REG - 1)) * (1.0f / SS);

    for (int f = f0 + tid; f < f1; f += 256) {
        uint32_t v = bb[f];
        int jlo = v & 255, jhi = (v >> 8) & 255, ilo = (v >> 16) & 255, ihi = (int)(v >> 24);
        if (jlo > rj0 + REG - 1 || jhi < rj0 || ilo > ri0 + REG - 1 || ihi < ri0) continue;
        PackedCoef P = pb[f];
        float b0a = __builtin_fmaf(P.q0.y, cxa, P.q0.x), b0b = __builtin_fmaf(P.q0.y, cxb, P.q0.x);
        float w0aa = __builtin_fmaf(P.q0.z, cya, b0a), w0ab = __builtin_fmaf(P.q0.z, cyb, b0a);
        float w0ba = __builtin_fmaf(P.q0.z, cya, b0b), w0bb = __builtin_fmaf(P.q0.z, cyb, b0b);
        float b1a = __builtin_fmaf(P.q1.x, cxa, P.q0.w), b1b = __builtin_fmaf(P.q1.x, cxb, P.q0.w);
        float w1aa = __builtin_fmaf(P.q1.y, cya, b1a), w1ab = __builtin_fmaf(P.q1.y, cyb, b1a);
        float w1ba = __builtin_fmaf(P.q1.y, cya, b1b), w1bb = __builtin_fmaf(P.q1.y, cyb, b1b);
        float w2aa = (1.0f - w0aa) - w1aa, w2ab = (1.0f - w0ab) - w1ab;
        float w2ba = (1.0f - w0ba) - w1ba, w2bb = (1.0f - w0bb) - w1bb;

        float m0n = fminf(fminf(w0aa, w0ab), fminf(w0ba, w0bb));
        float m0x = fmaxf(fmaxf(w0aa, w0ab), fmaxf(w0ba, w0bb));
        float m1n = fminf(fminf(w1aa, w1ab), fminf(w1ba, w1bb));
        float m1x = fmaxf(fmaxf(w1aa, w1ab), fmaxf(w1ba, w1bb));
        float m2n = fminf(fminf(w2aa, w2ab), fminf(w2ba, w2bb));
        float m2x = fmaxf(fmaxf(w2aa, w2ab), fmaxf(w2ba, w2bb));

        float Rm = 2.0f * P.q2.y;
        if (m0x < -Rm || m1x < -Rm || m2x < -Rm) continue;   // fully outside an edge

        // zinv upper bound over region + conservative margin (clamped >= 0)
        float za = __builtin_fmaf(P.q1.z, cxa, P.q2.x), zbq = __builtin_fmaf(P.q1.z, cxb, P.q2.x);
        float z_aa = __builtin_fmaf(P.q1.w, cya, za),  z_ab = __builtin_fmaf(P.q1.w, cyb, za);
        float z_ba = __builtin_fmaf(P.q1.w, cya, zbq), z_bb = __builtin_fmaf(P.q1.w, cyb, zbq);
        float cmax = fmaxf(fmaxf(z_aa, z_ab), fmaxf(z_ba, z_bb));
        float key = fmaxf(cmax + __builtin_fmaf(fabsf(cmax), 1e-6f, 1e-5f), 0.0f);

        bool full = (m0n > Rm && m1n > Rm && m2n > Rm);
        if (full) {
            int q = atomicAdd(&cnt_f, 1);
            if (q < CAPF) {
                fullr[q] = make_float4(P.q2.x, P.q1.z, P.q1.w, key);
                fkey[q] = key;
                continue;
            }
        }
        int p = atomicAdd(&cnt_p, 1);
        if (p < CAPP) {
            pool[3 * p + 0] = P.q0; pool[3 * p + 1] = P.q1; pool[3 * p + 2] = P.q2;
            sbb[p] = v;
            skey[p] = key;
        } else {
            int o = atomicAdd(&cnt_o, 1);
            if (o < OVN) ovl[o] = (uint16_t)f;
        }
    }
    __syncthreads();

    const int np = min(cnt_p, CAPP), nf = min(cnt_f, CAPF), no = min(cnt_o, OVN);
    const int np16 = (np + 15) & ~15;
    const int nf16 = (nf + 15) & ~15;
    // pad keys so grouped reads are safe (key 0 is always skipped: lanemin >= 0)
    for (int i = np + tid; i < np16; i += 256) skey[i] = 0.0f;
    for (int i = nf + tid; i < nf16; i += 256) fkey[i] = 0.0f;
    __syncthreads();

    // ---- phase 2 ----
    const int lane = tid & 63, w = tid >> 6;
    const int wj0 = rj0 + ((w & 1) << 4);
    const int wi0 = ri0 + ((w >> 1) << 4);
    const int j = wj0 + (lane & 15);
    const int i0r = wi0 + (lane >> 4);                 // rows i0r + 4r
    const float px = (float)(2 * j + 1 - SS) * (1.0f / SS);
    const float py0 = (float)(SS - 1 - 2 * (i0r + 0))  * (1.0f / SS);
    const float py1 = (float)(SS - 1 - 2 * (i0r + 4))  * (1.0f / SS);
    const float py2 = (float)(SS - 1 - 2 * (i0r + 8))  * (1.0f / SS);
    const float py3 = (float)(SS - 1 - 2 * (i0r + 12)) * (1.0f / SS);

    float best0 = 0.0f, best1 = 0.0f, best2 = 0.0f, best3 = 0.0f;

    // full-inside faces first (cheap; raises best for occlusion skips)
    for (int base = 0; base < nf16; base += 16) {
        float lm = wave_min_f(fminf(fminf(best0, best1), fminf(best2, best3)));
        for (int g = base; g < base + 16; g += 4) {
            float4 kk = *reinterpret_cast<const float4*>(&fkey[g]);
            float gmax = fmaxf(fmaxf(kk.x, kk.y), fmaxf(kk.z, kk.w));
            if (gmax <= lm) continue;                  // uniform branch
            #pragma unroll
            for (int u = 0; u < 4; ++u) {
                float key = (u == 0) ? kk.x : (u == 1) ? kk.y : (u == 2) ? kk.z : kk.w;
                if (key <= lm) continue;
                float4 z = fullr[g + u];
                float zb = __builtin_fmaf(z.y, px, z.x);
                best0 = fmaxf(best0, __builtin_fmaf(z.z, py0, zb));
                best1 = fmaxf(best1, __builtin_fmaf(z.z, py1, zb));
                best2 = fmaxf(best2, __builtin_fmaf(z.z, py2, zb));
                best3 = fmaxf(best3, __builtin_fmaf(z.z, py3, zb));
            }
        }
    }

    // partial faces: windowed wave_min occlusion skip (grouped x4) -> bbox -> body
    for (int base = 0; base < np16; base += 16) {
        float lm = wave_min_f(fminf(fminf(best0, best1), fminf(best2, best3)));
        for (int g = base; g < base + 16; g += 4) {
            float4 kk = *reinterpret_cast<const float4*>(&skey[g]);
            float gmax = fmaxf(fmaxf(kk.x, kk.y), fmaxf(kk.z, kk.w));
            if (gmax <= lm) continue;                  // uniform branch: skip 4 faces
            #pragma unroll
            for (int u = 0; u < 4; ++u) {
                float key = (u == 0) ? kk.x : (u == 1) ? kk.y : (u == 2) ? kk.z : kk.w;
                if (key <= lm) continue;               // occluded for whole wave
                int k = g + u;
                uint32_t bv = sbb[k];
                int jlo = bv & 255, jhi = (bv >> 8) & 255, ilo = (bv >> 16) & 255, ihi = (int)(bv >> 24);
                if (jlo > wj0 + 15 || jhi < wj0 || ilo > wi0 + 15 || ihi < wi0) continue;
                face_body(pool[3 * k + 0], pool[3 * k + 1], pool[3 * k + 2],
                          px, py0, py1, py2, py3, verts, faces, N, b,
                          best0, best1, best2, best3);
            }
        }
    }

    // overflow faces (rare): direct from global
    for (int k = 0; k < no; ++k) {
        int fid = __builtin_amdgcn_readfirstlane((int)ovl[k]);
        float4 q2 = pb[fid].q2;
        uint32_t bv = __float_as_uint(q2.z);
        int jlo = bv & 255, jhi = (bv >> 8) & 255, ilo = (bv >> 16) & 255, ihi = (int)(bv >> 24);
        if (jlo > wj0 + 15 || jhi < wj0 || ilo > wi0 + 15 || ihi < wi0) continue;
        face_body(pb[fid].q0, pb[fid].q1, q2,
                  px, py0, py1, py2, py3, verts, faces, N, b,
                  best0, best1, best2, best3);
    }

    const size_t base = (size_t)b * (SS * SS) + (size_t)i0r * SS + j;
    if (best0 > 0.0f) atomicMin(&zu[base + 0 * 4 * SS], __float_as_uint(1.0f / best0));
    if (best1 > 0.0f) atomicMin(&zu[base + 1 * 4 * SS], __float_as_uint(1.0f / best1));
    if (best2 > 0.0f) atomicMin(&zu[base + 2 * 4 * SS], __float_as_uint(1.0f / best2));
    if (best3 > 0.0f) atomicMin(&zu[base + 3 * 4 * SS], __float_as_uint(1.0f / best3));
}

// ---------------- final: uint zbuf -> (sil, z) ----------------
__global__ void nmr_final(float* __restrict__ out, int B)
{
    int idx = blockIdx.x * 256 + threadIdx.x;
    if (idx >= B * SS * SS) return;
    uint32_t* zu = (uint32_t*)(out + (size_t)B * SS * SS);
    uint32_t u = zu[idx];
    bool cov = (u != 0xFFFFFFFFu);
    out[idx] = cov ? 1.0f : 0.0f;
    ((float*)zu)[idx] = cov ? __uint_as_float(u) : FAR_F;
}

// ---------------- host ----------------
extern "C" void kernel_launch(void* const* d_in, const int* in_sizes, int n_in,
                              void* d_out, int out_size, void* d_ws, size_t ws_size,
                              hipStream_t stream)
{
    const float* verts = (const float*)d_in[0];
    const int*   faces = (const int*)d_in[1];
    float* out = (float*)d_out;

    const int B = out_size / (2 * SS * SS);          // 16
    const int F = in_sizes[1] / 3;                   // 1538
    const int N = in_sizes[0] / (3 * B);             // 778

    PackedCoef* pc = (PackedCoef*)d_ws;
    uint32_t*  bbx = (uint32_t*)((char*)d_ws + (size_t)B * F * sizeof(PackedCoef));
    uint32_t*  zu  = (uint32_t*)(out + (size_t)B * SS * SS);

    hipMemsetAsync(zu, 0xFF, (size_t)B * SS * SS * sizeof(uint32_t), stream);

    const int total = B * F;
    nmr_prep<<<(total + 255) / 256, 256, 0, stream>>>(verts, faces, pc, bbx, B, N, F);

    const int CH = (F + NCH - 1) / NCH;              // 513
    nmr_raster<<<B * NREG * NCH, 256, 0, stream>>>(pc, bbx, verts, faces, zu, B, N, F, CH);

    nmr_final<<<(B * SS * SS + 255) / 256, 256, 0, stream>>>(out, B);
}